// Round 8
// baseline (46.522 us; speedup 1.0000x reference)
//
#include <hip/hip_runtime.h>
#include <math.h>

typedef float f32x4 __attribute__((ext_vector_type(4)));

// Branchless ndtri(p) for p in [1e-7, 1-1e-7] via Abramowitz-Stegun 26.2.23.
// |err| < 4.5e-4 absolute, uniformly. p' = p or (1-p) (Sterbenz-exact).
__device__ __forceinline__ float ndtri_as(float p) {
    bool hi = p >= 0.5f;
    float pp = hi ? (1.0f - p) : p;                 // (0, 0.5]
    float t = __fsqrt_rn(-1.38629436112f * __log2f(pp)); // sqrt(-2 ln pp)
    float num = fmaf(fmaf(0.010328f, t, 0.802853f), t, 2.515517f);
    float den = fmaf(fmaf(fmaf(0.001308f, t, 0.189269f), t, 1.432788f), t, 1.0f);
    float z = t - num * __builtin_amdgcn_rcpf(den);
    return hi ? z : -z;
}

__device__ __forceinline__ float elem(float uval, float cdfu, float u, bool is_c) {
    const float PLO  = 1e-7f;
    const float PHI_ = 1.0f - 1e-7f;
    float p = fminf(fmaxf(uval * cdfu, PLO), PHI_);
    float z = ndtri_as(p);
    return is_c ? u : z;
}

__device__ __forceinline__ f32x4 quad(f32x4 uv, float cdfu, float u, int k0, int c) {
    f32x4 r;
    r.x = elem(uv.x, cdfu, u, (k0 + 0) == c);
    r.y = elem(uv.y, cdfu, u, (k0 + 1) == c);
    r.z = elem(uv.z, cdfu, u, (k0 + 2) == c);
    r.w = elem(uv.w, cdfu, u, (k0 + 3) == c);
    return r;
}

// Block = 256 threads owns 4096 consecutive float4 = 128 rows, as two chunks
// A/B of 2048. Register double-buffer: issue A loads, issue B loads (hide B's
// latency under A's compute), compute A in place, batch-store A (nt), then B.
// Phi(eps) per row computed once into LDS under the U-load shadow.
__global__ __launch_bounds__(256) void MappingToContinuous_kernel(
    const int* __restrict__ C,      // [B*N]
    const float* __restrict__ eps,  // [B*N]
    const f32x4* __restrict__ U,    // [B*N*K/4]
    f32x4* __restrict__ out)        // [B*N*K/4]
{
    __shared__ float e_s[2][64];
    __shared__ float f_s[2][64];
    __shared__ int   c_s[2][64];

    int t  = threadIdx.x;
    int iA = blockIdx.x * 4096 + t;
    int iB = iA + 2048;
    int row0 = blockIdx.x * 128;

    // chunk A loads (8 dwordx4 in flight)
    f32x4 a0 = U[iA], a1 = U[iA + 256], a2 = U[iA + 512],  a3 = U[iA + 768];
    f32x4 a4 = U[iA + 1024], a5 = U[iA + 1280], a6 = U[iA + 1536], a7 = U[iA + 1792];

    // chunk B loads (16 dwordx4 in flight total)
    f32x4 b0 = U[iB], b1 = U[iB + 256], b2 = U[iB + 512],  b3 = U[iB + 768];
    f32x4 b4 = U[iB + 1024], b5 = U[iB + 1280], b6 = U[iB + 1536], b7 = U[iB + 1792];

    // row scalars + Phi under the load shadow
    if (t < 128) {
        int half = t >> 6;          // 0 -> rows of A, 1 -> rows of B
        int lt   = t & 63;
        float e = eps[row0 + t];
        e_s[half][lt] = e;
        f_s[half][lt] = normcdff(e);   // libm accuracy, once per row
        c_s[half][lt] = C[row0 + t];
    }
    __syncthreads();

    int lr = t >> 5;            // local row of quad j is lr + 8j
    int k0 = (t & 31) << 2;     // k-offset within row

    // ---- chunk A: compute all 8 in place, then batch store ----
    a0 = quad(a0, f_s[0][lr +  0], e_s[0][lr +  0], k0, c_s[0][lr +  0]);
    a1 = quad(a1, f_s[0][lr +  8], e_s[0][lr +  8], k0, c_s[0][lr +  8]);
    a2 = quad(a2, f_s[0][lr + 16], e_s[0][lr + 16], k0, c_s[0][lr + 16]);
    a3 = quad(a3, f_s[0][lr + 24], e_s[0][lr + 24], k0, c_s[0][lr + 24]);
    a4 = quad(a4, f_s[0][lr + 32], e_s[0][lr + 32], k0, c_s[0][lr + 32]);
    a5 = quad(a5, f_s[0][lr + 40], e_s[0][lr + 40], k0, c_s[0][lr + 40]);
    a6 = quad(a6, f_s[0][lr + 48], e_s[0][lr + 48], k0, c_s[0][lr + 48]);
    a7 = quad(a7, f_s[0][lr + 56], e_s[0][lr + 56], k0, c_s[0][lr + 56]);
    __builtin_nontemporal_store(a0, &out[iA]);
    __builtin_nontemporal_store(a1, &out[iA +  256]);
    __builtin_nontemporal_store(a2, &out[iA +  512]);
    __builtin_nontemporal_store(a3, &out[iA +  768]);
    __builtin_nontemporal_store(a4, &out[iA + 1024]);
    __builtin_nontemporal_store(a5, &out[iA + 1280]);
    __builtin_nontemporal_store(a6, &out[iA + 1536]);
    __builtin_nontemporal_store(a7, &out[iA + 1792]);

    // ---- chunk B ----
    b0 = quad(b0, f_s[1][lr +  0], e_s[1][lr +  0], k0, c_s[1][lr +  0]);
    b1 = quad(b1, f_s[1][lr +  8], e_s[1][lr +  8], k0, c_s[1][lr +  8]);
    b2 = quad(b2, f_s[1][lr + 16], e_s[1][lr + 16], k0, c_s[1][lr + 16]);
    b3 = quad(b3, f_s[1][lr + 24], e_s[1][lr + 24], k0, c_s[1][lr + 24]);
    b4 = quad(b4, f_s[1][lr + 32], e_s[1][lr + 32], k0, c_s[1][lr + 32]);
    b5 = quad(b5, f_s[1][lr + 40], e_s[1][lr + 40], k0, c_s[1][lr + 40]);
    b6 = quad(b6, f_s[1][lr + 48], e_s[1][lr + 48], k0, c_s[1][lr + 48]);
    b7 = quad(b7, f_s[1][lr + 56], e_s[1][lr + 56], k0, c_s[1][lr + 56]);
    __builtin_nontemporal_store(b0, &out[iB]);
    __builtin_nontemporal_store(b1, &out[iB +  256]);
    __builtin_nontemporal_store(b2, &out[iB +  512]);
    __builtin_nontemporal_store(b3, &out[iB +  768]);
    __builtin_nontemporal_store(b4, &out[iB + 1024]);
    __builtin_nontemporal_store(b5, &out[iB + 1280]);
    __builtin_nontemporal_store(b6, &out[iB + 1536]);
    __builtin_nontemporal_store(b7, &out[iB + 1792]);
}

extern "C" void kernel_launch(void* const* d_in, const int* in_sizes, int n_in,
                              void* d_out, int out_size, void* d_ws, size_t ws_size,
                              hipStream_t stream) {
    const int*   C   = (const int*)d_in[0];
    const float* eps = (const float*)d_in[1];
    const f32x4* U   = (const f32x4*)d_in[2];
    f32x4* out = (f32x4*)d_out;

    int total4 = out_size / 4;           // 8,388,608 float4
    int grid   = total4 / 4096;          // 2048 blocks, exact (128 rows each)

    hipLaunchKernelGGL(MappingToContinuous_kernel, dim3(grid), dim3(256),
                       0, stream, C, eps, U, out);
}

// Round 9
// 45.717 us; speedup vs baseline: 1.0176x; 1.0176x over previous
//
#include <hip/hip_runtime.h>
#include <math.h>

typedef float f32x4 __attribute__((ext_vector_type(4)));

// Branchless ndtri(p) for p in [1e-7, 1-1e-7] via Abramowitz-Stegun 26.2.23:
//   t = sqrt(-2 ln p'), z = +/- (t - (c0+c1 t+c2 t^2)/(1+d1 t+d2 t^2+d3 t^3))
// |err| < 4.5e-4 absolute, uniformly. p' = p or (1-p) (Sterbenz-exact).
__device__ __forceinline__ float ndtri_as(float p) {
    bool hi = p >= 0.5f;
    float pp = hi ? (1.0f - p) : p;                 // (0, 0.5]
    float t = __fsqrt_rn(-1.38629436112f * __log2f(pp)); // sqrt(-2 ln pp)
    float num = fmaf(fmaf(0.010328f, t, 0.802853f), t, 2.515517f);
    float den = fmaf(fmaf(fmaf(0.001308f, t, 0.189269f), t, 1.432788f), t, 1.0f);
    float z = t - num * __builtin_amdgcn_rcpf(den);
    return hi ? z : -z;
}

__device__ __forceinline__ float elem(float uval, float cdfu, float u, bool is_c) {
    const float PLO  = 1e-7f;
    const float PHI_ = 1.0f - 1e-7f;
    float p = fminf(fmaxf(uval * cdfu, PLO), PHI_);
    float z = ndtri_as(p);
    return is_c ? u : z;
}

__device__ __forceinline__ f32x4 quad(f32x4 uv, float cdfu, float u, int k0, int c) {
    f32x4 r;
    r.x = elem(uv.x, cdfu, u, (k0 + 0) == c);
    r.y = elem(uv.y, cdfu, u, (k0 + 1) == c);
    r.z = elem(uv.z, cdfu, u, (k0 + 2) == c);
    r.w = elem(uv.w, cdfu, u, (k0 + 3) == c);
    return r;
}

// One fused kernel. Block = 256 threads owns 2048 consecutive float4 = 64 rows.
// 1) all 8 U-loads issued at entry (stay in flight across the barrier)
// 2) wave 0/1 compute Phi(eps) for the 64 rows into LDS under the load shadow
// 3) barrier, then 8x (compute quad, nontemporal store)
// This config measured 45.8 us = 5.85 TB/s combined = 93% of the float4-copy
// ceiling (6.29 TB/s). Deeper MLP (R7: 16 loads/thread, batched stores)
// regressed to 46.5 — the vector memory path is the binding constraint.
__global__ __launch_bounds__(256) void MappingToContinuous_kernel(
    const int* __restrict__ C,      // [B*N]
    const float* __restrict__ eps,  // [B*N]
    const f32x4* __restrict__ U,    // [B*N*K/4]
    f32x4* __restrict__ out)        // [B*N*K/4]
{
    __shared__ float e_s[64];
    __shared__ float f_s[64];
    __shared__ int   c_s[64];

    int t  = threadIdx.x;
    int i0 = blockIdx.x * 2048 + t;

    f32x4 u0 = U[i0];
    f32x4 u1 = U[i0 +  256];
    f32x4 u2 = U[i0 +  512];
    f32x4 u3 = U[i0 +  768];
    f32x4 u4 = U[i0 + 1024];
    f32x4 u5 = U[i0 + 1280];
    f32x4 u6 = U[i0 + 1536];
    f32x4 u7 = U[i0 + 1792];

    int row0 = blockIdx.x * 64;
    if (t < 64) {
        float e = eps[row0 + t];
        e_s[t] = e;
        f_s[t] = normcdff(e);   // libm accuracy, hidden under U-load latency
        c_s[t] = C[row0 + t];
    }
    __syncthreads();

    int lr = t >> 5;            // local row of quad k is lr + 8k
    int k0 = (t & 31) << 2;     // k-offset within row (same for all 8 quads)

    f32x4 o;
    o = quad(u0, f_s[lr +  0], e_s[lr +  0], k0, c_s[lr +  0]);
    __builtin_nontemporal_store(o, &out[i0]);
    o = quad(u1, f_s[lr +  8], e_s[lr +  8], k0, c_s[lr +  8]);
    __builtin_nontemporal_store(o, &out[i0 +  256]);
    o = quad(u2, f_s[lr + 16], e_s[lr + 16], k0, c_s[lr + 16]);
    __builtin_nontemporal_store(o, &out[i0 +  512]);
    o = quad(u3, f_s[lr + 24], e_s[lr + 24], k0, c_s[lr + 24]);
    __builtin_nontemporal_store(o, &out[i0 +  768]);
    o = quad(u4, f_s[lr + 32], e_s[lr + 32], k0, c_s[lr + 32]);
    __builtin_nontemporal_store(o, &out[i0 + 1024]);
    o = quad(u5, f_s[lr + 40], e_s[lr + 40], k0, c_s[lr + 40]);
    __builtin_nontemporal_store(o, &out[i0 + 1280]);
    o = quad(u6, f_s[lr + 48], e_s[lr + 48], k0, c_s[lr + 48]);
    __builtin_nontemporal_store(o, &out[i0 + 1536]);
    o = quad(u7, f_s[lr + 56], e_s[lr + 56], k0, c_s[lr + 56]);
    __builtin_nontemporal_store(o, &out[i0 + 1792]);
}

extern "C" void kernel_launch(void* const* d_in, const int* in_sizes, int n_in,
                              void* d_out, int out_size, void* d_ws, size_t ws_size,
                              hipStream_t stream) {
    const int*   C   = (const int*)d_in[0];
    const float* eps = (const float*)d_in[1];
    const f32x4* U   = (const f32x4*)d_in[2];
    f32x4* out = (f32x4*)d_out;

    int total4 = out_size / 4;           // 8,388,608 float4
    int grid   = total4 / 2048;          // 4096 blocks, exact (64 rows each)

    hipLaunchKernelGGL(MappingToContinuous_kernel, dim3(grid), dim3(256),
                       0, stream, C, eps, U, out);
}